// Round 8
// baseline (22.127 us; speedup 1.0000x reference)
//
#include <hip/hip_runtime.h>

#define WPAD 68              // transposed-W LDS row stride (floats)
#define FMAGIC 0x5EEDBEA7u   // != 0xAAAAAAAA poison; collision chance negligible

// Single dispatch. Block bc = b*64+ch owns rows m0..m0+15 of batch b.
// Phase A: a-dot -> chunk max -> wsmax + release flag.
// Overlap: c-dot while other blocks finish phase A.
// Phase B: spin on batch flags -> acquire fence -> amax gather -> add -> out.
__global__ __launch_bounds__(256) void pe_fused(const float* __restrict__ x,
                                                const float* __restrict__ W,
                                                const float* __restrict__ bias,
                                                float* __restrict__ wsmax,
                                                unsigned int* __restrict__ flags,
                                                float* __restrict__ out) {
    __shared__ float W1t[64 * WPAD];
    __shared__ float W2t[64 * WPAD];
    __shared__ float xs[16 * WPAD];
    __shared__ float red[16 * 64];
    __shared__ float addv[64];

    const int t  = threadIdx.x;
    const int bc = blockIdx.x;          // b*64 + ch
    const int b  = bc >> 6;
    const int m0 = (bc & 63) << 4;
    const int r  = t >> 4;
    const int og = t & 15;

    // ---- stage x (1 load, issued first) + both W halves transposed (8 loads) ----
    {
        const float4* x4 = (const float4*)(x + ((size_t)b * 1024 + m0) * 64);
        float4 xv = x4[t];
        *(float4*)&xs[(t >> 4) * WPAD + 4 * (t & 15)] = xv;
    }
    const float4* W4 = (const float4*)W;          // W row = 32 float4
    #pragma unroll
    for (int i = 0; i < 4; ++i) {
        int id = t + 256 * i;
        int o = id >> 4, q = id & 15;
        float4 w1 = W4[o * 32 + q];               // W1 half
        float4 w2 = W4[o * 32 + 16 + q];          // W2 half
        W1t[(4 * q + 0) * WPAD + o] = w1.x;
        W1t[(4 * q + 1) * WPAD + o] = w1.y;
        W1t[(4 * q + 2) * WPAD + o] = w1.z;
        W1t[(4 * q + 3) * WPAD + o] = w1.w;
        W2t[(4 * q + 0) * WPAD + o] = w2.x;
        W2t[(4 * q + 1) * WPAD + o] = w2.y;
        W2t[(4 * q + 2) * WPAD + o] = w2.z;
        W2t[(4 * q + 3) * WPAD + o] = w2.w;
    }
    __syncthreads();

    const float* xr = &xs[r * WPAD];

    // ---- phase A: a-dot (shortest path to signaling) ----
    float ax = 0.f, ay = 0.f, az = 0.f, aw = 0.f;
    #pragma unroll
    for (int q = 0; q < 16; ++q) {
        float4 xv = *(const float4*)&xr[4 * q];
        float4 w0 = *(const float4*)&W1t[(4 * q + 0) * WPAD + og * 4];
        float4 w1 = *(const float4*)&W1t[(4 * q + 1) * WPAD + og * 4];
        float4 w2 = *(const float4*)&W1t[(4 * q + 2) * WPAD + og * 4];
        float4 w3 = *(const float4*)&W1t[(4 * q + 3) * WPAD + og * 4];
        ax += xv.x * w0.x + xv.y * w1.x + xv.z * w2.x + xv.w * w3.x;
        ay += xv.x * w0.y + xv.y * w1.y + xv.z * w2.y + xv.w * w3.y;
        az += xv.x * w0.z + xv.y * w1.z + xv.z * w2.z + xv.w * w3.z;
        aw += xv.x * w0.w + xv.y * w1.w + xv.z * w2.w + xv.w * w3.w;
    }
    *(float4*)&red[r * 64 + og * 4] = make_float4(ax, ay, az, aw);
    __syncthreads();
    if (t < 64) {
        float v = red[t];
        #pragma unroll
        for (int rr = 1; rr < 16; ++rr) v = fmaxf(v, red[rr * 64 + t]);
        wsmax[(size_t)bc * 64 + t] = v;
    }
    __syncthreads();   // all wsmax stores drained block-wide (vmcnt(0) at barrier)
    if (t == 0)
        __hip_atomic_store(&flags[bc], FMAGIC, __ATOMIC_RELEASE,
                           __HIP_MEMORY_SCOPE_AGENT);

    // ---- c-dot: overlaps other blocks finishing phase A ----
    float cx = 0.f, cy = 0.f, cz = 0.f, cw = 0.f;
    #pragma unroll
    for (int q = 0; q < 16; ++q) {
        float4 xv = *(const float4*)&xr[4 * q];
        float4 w0 = *(const float4*)&W2t[(4 * q + 0) * WPAD + og * 4];
        float4 w1 = *(const float4*)&W2t[(4 * q + 1) * WPAD + og * 4];
        float4 w2 = *(const float4*)&W2t[(4 * q + 2) * WPAD + og * 4];
        float4 w3 = *(const float4*)&W2t[(4 * q + 3) * WPAD + og * 4];
        cx += xv.x * w0.x + xv.y * w1.x + xv.z * w2.x + xv.w * w3.x;
        cy += xv.x * w0.y + xv.y * w1.y + xv.z * w2.y + xv.w * w3.y;
        cz += xv.x * w0.z + xv.y * w1.z + xv.z * w2.z + xv.w * w3.z;
        cw += xv.x * w0.w + xv.y * w1.w + xv.z * w2.w + xv.w * w3.w;
    }

    // ---- wait for this batch's 64 chunk flags (lane t&63 -> one flag) ----
    {
        const unsigned int* fp = flags + (b << 6) + (t & 63);
        while (__hip_atomic_load(fp, __ATOMIC_RELAXED,
                                 __HIP_MEMORY_SCOPE_AGENT) != FMAGIC)
            __builtin_amdgcn_s_sleep(1);
    }
    __syncthreads();                                    // whole block saw all flags
    __builtin_amdgcn_fence(__ATOMIC_ACQUIRE, "agent");  // invalidate stale cache

    // ---- amax gather: thread t -> col o=t&63, segment g=t>>6 ----
    {
        const int o = t & 63, g = t >> 6;
        const float* wp = wsmax + (size_t)(b << 6) * 64 + o;
        float v = wp[(size_t)g * 64];
        #pragma unroll
        for (int s = 1; s < 16; ++s) v = fmaxf(v, wp[(size_t)(g + 4 * s) * 64]);
        red[g * 64 + o] = v;          // red reusable: barrier since last use
    }
    __syncthreads();
    if (t < 64)
        addv[t] = fmaxf(fmaxf(red[t], red[64 + t]),
                        fmaxf(red[128 + t], red[192 + t])) + bias[t];
    __syncthreads();

    float4 add = *(const float4*)&addv[og * 4];
    *(float4*)&out[((size_t)b * 1024 + m0 + r) * 64 + og * 4] =
        make_float4(cx + add.x, cy + add.y, cz + add.z, cw + add.w);
}

extern "C" void kernel_launch(void* const* d_in, const int* in_sizes, int n_in,
                              void* d_out, int out_size, void* d_ws, size_t ws_size,
                              hipStream_t stream) {
    const float* x    = (const float*)d_in[0];
    const float* W    = (const float*)d_in[1];
    const float* bias = (const float*)d_in[2];
    float* out   = (float*)d_out;
    float* wsmax = (float*)d_ws;                               // 64 KiB
    unsigned int* flags = (unsigned int*)((char*)d_ws + 65536); // 1 KiB

    pe_fused<<<dim3(256), dim3(256), 0, stream>>>(x, W, bias, wsmax, flags, out);
}

// Round 9
// 12.995 us; speedup vs baseline: 1.7027x; 1.7027x over previous
//
#include <hip/hip_runtime.h>

#define WPAD 68   // padded row stride (floats); 68*4=272 B keeps float4 rows 16B-aligned

// ---------------------------------------------------------------------------
// K1: per (b, 16-row chunk) compute a[b,n,o] = x[b,n,:]·W1[o,:] and reduce
//     max over the chunk's 16 rows -> wsmax[b][ch][o]  (16 KB total)
// ---------------------------------------------------------------------------
__global__ __launch_bounds__(256) void pe_k1(const float* __restrict__ x,
                                             const float* __restrict__ W,
                                             float* __restrict__ wsmax) {
    __shared__ float Wt[64 * WPAD];   // Wt[k*WPAD+o] = W1[o][k]
    __shared__ float xs[16 * WPAD];
    __shared__ float red[16 * 64];

    const int t  = threadIdx.x;
    const int b  = blockIdx.x >> 6;
    const int ch = blockIdx.x & 63;
    const int m0 = ch << 4;

    // stage W1^T (16 KB). id -> o=id>>4 (row), q=id&15 (k-quad)
    const float4* W4 = (const float4*)W;   // W row = 128 floats = 32 float4
    #pragma unroll
    for (int i = 0; i < 4; ++i) {
        int id = t + 256 * i;
        int o = id >> 4, q = id & 15;
        float4 wv = W4[o * 32 + q];        // W1 half: k = 4q..4q+3
        Wt[(4 * q + 0) * WPAD + o] = wv.x;
        Wt[(4 * q + 1) * WPAD + o] = wv.y;
        Wt[(4 * q + 2) * WPAD + o] = wv.z;
        Wt[(4 * q + 3) * WPAD + o] = wv.w;
    }
    // stage x rows (4 KB)
    {
        const float4* x4 = (const float4*)(x + ((size_t)b * 1024 + m0) * 64);
        float4 xv = x4[t];
        *(float4*)&xs[(t >> 4) * WPAD + 4 * (t & 15)] = xv;
    }
    __syncthreads();

    const int r  = t >> 4;
    const int og = t & 15;
    const float* xr = &xs[r * WPAD];
    float ax = 0.f, ay = 0.f, az = 0.f, aw = 0.f;

    #pragma unroll
    for (int q = 0; q < 16; ++q) {
        float4 xq = *(const float4*)&xr[4 * q];
        float4 w0 = *(const float4*)&Wt[(4 * q + 0) * WPAD + og * 4];
        float4 w1 = *(const float4*)&Wt[(4 * q + 1) * WPAD + og * 4];
        float4 w2 = *(const float4*)&Wt[(4 * q + 2) * WPAD + og * 4];
        float4 w3 = *(const float4*)&Wt[(4 * q + 3) * WPAD + og * 4];
        ax += xq.x * w0.x; ay += xq.x * w0.y; az += xq.x * w0.z; aw += xq.x * w0.w;
        ax += xq.y * w1.x; ay += xq.y * w1.y; az += xq.y * w1.z; aw += xq.y * w1.w;
        ax += xq.z * w2.x; ay += xq.z * w2.y; az += xq.z * w2.z; aw += xq.z * w2.w;
        ax += xq.w * w3.x; ay += xq.w * w3.y; az += xq.w * w3.z; aw += xq.w * w3.w;
    }
    *(float4*)&red[r * 64 + og * 4] = make_float4(ax, ay, az, aw);
    __syncthreads();

    if (t < 64) {
        float v = red[t];
        #pragma unroll
        for (int rr = 1; rr < 16; ++rr) v = fmaxf(v, red[rr * 64 + t]);
        wsmax[((size_t)(b << 6) + ch) * 64 + t] = v;
    }
}

// ---------------------------------------------------------------------------
// K2: per (b, 16-row chunk):
//   amax[o] = max_ch wsmax[b][ch][o];  out[b,m,o] = x[b,m,:]·W2[o,:] + amax[o] + bias[o]
//   out written exactly once, coalesced float4.
// ---------------------------------------------------------------------------
__global__ __launch_bounds__(256) void pe_k2(const float* __restrict__ x,
                                             const float* __restrict__ W,
                                             const float* __restrict__ bias,
                                             const float* __restrict__ wsmax,
                                             float* __restrict__ out) {
    __shared__ float Wt[64 * WPAD];   // Wt[k*WPAD+o] = W2[o][k]
    __shared__ float xs[16 * WPAD];
    __shared__ float amx[4 * 64];
    __shared__ float addv[64];

    const int t  = threadIdx.x;
    const int b  = blockIdx.x >> 6;
    const int ch = blockIdx.x & 63;
    const int m0 = ch << 4;

    // stage W2^T
    const float4* W4 = (const float4*)W;
    #pragma unroll
    for (int i = 0; i < 4; ++i) {
        int id = t + 256 * i;
        int o = id >> 4, q = id & 15;
        float4 wv = W4[o * 32 + 16 + q];   // W2 half: k = 64 + 4q ..
        Wt[(4 * q + 0) * WPAD + o] = wv.x;
        Wt[(4 * q + 1) * WPAD + o] = wv.y;
        Wt[(4 * q + 2) * WPAD + o] = wv.z;
        Wt[(4 * q + 3) * WPAD + o] = wv.w;
    }
    // stage x rows
    {
        const float4* x4 = (const float4*)(x + ((size_t)b * 1024 + m0) * 64);
        float4 xv = x4[t];
        *(float4*)&xs[(t >> 4) * WPAD + 4 * (t & 15)] = xv;
    }
    // partial amax: thread t handles o = t&63 over chunks {g, g+4, ..., g+60}
    {
        const int o = t & 63, g = t >> 6;
        const float* wp = wsmax + (size_t)b * 4096 + o;
        float v = wp[(size_t)g * 64];
        #pragma unroll
        for (int s = 1; s < 16; ++s) v = fmaxf(v, wp[(size_t)(g + 4 * s) * 64]);
        amx[g * 64 + o] = v;
    }
    __syncthreads();
    if (t < 64) {
        float v = fmaxf(fmaxf(amx[t], amx[64 + t]), fmaxf(amx[128 + t], amx[192 + t]));
        addv[t] = v + bias[t];
    }
    __syncthreads();

    const int r  = t >> 4;
    const int og = t & 15;
    const float* xr = &xs[r * WPAD];
    float4 add = *(const float4*)&addv[og * 4];
    float cx = add.x, cy = add.y, cz = add.z, cw = add.w;

    #pragma unroll
    for (int q = 0; q < 16; ++q) {
        float4 xq = *(const float4*)&xr[4 * q];
        float4 w0 = *(const float4*)&Wt[(4 * q + 0) * WPAD + og * 4];
        float4 w1 = *(const float4*)&Wt[(4 * q + 1) * WPAD + og * 4];
        float4 w2 = *(const float4*)&Wt[(4 * q + 2) * WPAD + og * 4];
        float4 w3 = *(const float4*)&Wt[(4 * q + 3) * WPAD + og * 4];
        cx += xq.x * w0.x; cy += xq.x * w0.y; cz += xq.x * w0.z; cw += xq.x * w0.w;
        cx += xq.y * w1.x; cy += xq.y * w1.y; cz += xq.y * w1.z; cw += xq.y * w1.w;
        cx += xq.z * w2.x; cy += xq.z * w2.y; cz += xq.z * w2.z; cw += xq.z * w2.w;
        cx += xq.w * w3.x; cy += xq.w * w3.y; cz += xq.w * w3.z; cw += xq.w * w3.w;
    }

    size_t oidx = ((size_t)b * 1024 + (m0 + r)) * 64 + og * 4;
    *(float4*)&out[oidx] = make_float4(cx, cy, cz, cw);
}

extern "C" void kernel_launch(void* const* d_in, const int* in_sizes, int n_in,
                              void* d_out, int out_size, void* d_ws, size_t ws_size,
                              hipStream_t stream) {
    const float* x    = (const float*)d_in[0];
    const float* W    = (const float*)d_in[1];
    const float* bias = (const float*)d_in[2];
    float* out   = (float*)d_out;
    float* wsmax = (float*)d_ws;   // 4*64*64*4 = 64 KiB used

    pe_k1<<<4 * 64, 256, 0, stream>>>(x, W, wsmax);
    pe_k2<<<4 * 64, 256, 0, stream>>>(x, W, bias, wsmax, out);
}